// Round 9
// baseline (1154.323 us; speedup 1.0000x reference)
//
#include <hip/hip_runtime.h>
#include <hip/hip_bf16.h>

#define BB 8
#define EE 64
#define MM 128
#define SSN 32
#define DD 256
#define HH 8
#define DKK 32
#define WMAX 16
#define QCH 16   // queries per chunk in k_main2

// Build per-(b,e) mention lists: lst[(b*EE+e)*MM + k] = m-th mention with eid==e
__global__ void k_lists(const int* __restrict__ eid, int* __restrict__ cnt, int* __restrict__ lst) {
  int b = blockIdx.x;
  __shared__ int eid_s[MM];
  for (int m = threadIdx.x; m < MM; m += blockDim.x) eid_s[m] = eid[b * MM + m];
  __syncthreads();
  int e = threadIdx.x;  // blockDim = 64
  int c = 0;
  int* lp = lst + (b * EE + e) * MM;
  for (int m = 0; m < MM; ++m)
    if (eid_s[m] == e) lp[c++] = m;
  cnt[b * EE + e] = c;
}

// out[r, c] = sum_k A[src(r), k] * W[k, c] + bias[c], 4 rows/block
__global__ void k_proj(const float* __restrict__ A, const int* __restrict__ gather,
                       int rowsPerB, int srcRowsPerB,
                       const float* __restrict__ W, const float* __restrict__ bias,
                       float* __restrict__ out) {
  int r0 = blockIdx.x * 4;
  int c = threadIdx.x;  // 256 threads
  __shared__ float a_s[4][DD];
#pragma unroll
  for (int i = 0; i < 4; ++i) {
    int r = r0 + i;
    int b = r / rowsPerB, rr = r - b * rowsPerB;
    int sr = gather ? gather[b * rowsPerB + rr] : rr;
    if (sr < 0) sr = 0;
    if (sr >= srcRowsPerB) sr = srcRowsPerB - 1;
    a_s[i][c] = A[((size_t)b * srcRowsPerB + sr) * DD + c];
  }
  __syncthreads();
  float acc0 = 0.f, acc1 = 0.f, acc2 = 0.f, acc3 = 0.f;
  for (int k = 0; k < DD; ++k) {
    float w = W[(size_t)k * DD + c];
    acc0 = fmaf(a_s[0][k], w, acc0);
    acc1 = fmaf(a_s[1][k], w, acc1);
    acc2 = fmaf(a_s[2][k], w, acc2);
    acc3 = fmaf(a_s[3][k], w, acc3);
  }
  float bv = bias[c];
  out[((size_t)r0 + 0) * DD + c] = acc0 + bv;
  out[((size_t)r0 + 1) * DD + c] = acc1 + bv;
  out[((size_t)r0 + 2) * DD + c] = acc2 + bv;
  out[((size_t)r0 + 3) * DD + c] = acc3 + bv;
}

// Vsum[b, d] = sum_m V[b, m, d]
__global__ void k_vsum(const float* __restrict__ V, float* __restrict__ Vsum) {
  int b = blockIdx.x;
  int d = threadIdx.x;
  float s = 0.f;
  for (int m = 0; m < MM; ++m) s += V[((size_t)b * MM + m) * DD + d];
  Vsum[b * DD + d] = s;
}

// One block per (b, mask-entity em). Computes all 64 output rows for this mask set.
// side h (sideT=0): p = em*64 + q   (em = row i, q = query = col j)
// side t (sideT=1): p = q*64 + em   (q = query = row i, em = col j)
__global__ __launch_bounds__(256) void k_main2(
    const float* __restrict__ Q, const float* __restrict__ K,
    const float* __restrict__ V, const float* __restrict__ Vsum,
    const float* __restrict__ W3, const float* __restrict__ b3,
    const int* __restrict__ cnt, const int* __restrict__ lst,
    float* __restrict__ outp, int sideT) {
  int blk = blockIdx.x;  // b*EE + em
  int b = blk >> 6, em = blk & 63;
  int tid = threadIdx.x;
  __shared__ float Ks[WMAX][DD];
  __shared__ float Vs[WMAX][DD];
  __shared__ float wl[QCH][HH][WMAX];
  __shared__ float av[QCH][DD];
  __shared__ int lst_s[MM];
  __shared__ int cn_s;
  if (tid == 0) cn_s = cnt[blk];
  for (int m = tid; m < MM; m += 256) lst_s[m] = lst[blk * MM + m];
  __syncthreads();
  int cn = cn_s;
  const float scale = 0.17677669529663687f;  // 1/sqrt(32)

  if (cn == 0) {
    // all masked -> softmax uniform over all 128 mentions; same row for every q
    float acc = b3[tid];
    for (int d = 0; d < DD; ++d)
      acc = fmaf(Vsum[b * DD + d] * (1.0f / 128.0f), W3[(size_t)d * DD + tid], acc);
    for (int q = 0; q < EE; ++q) {
      int p = sideT ? (q * EE + em) : (em * EE + q);
      outp[((size_t)b * 4096 + p) * DD + tid] = acc;
    }
    return;
  }

  bool small = (cn <= WMAX);
  if (small) {
    for (int i = 0; i < cn; ++i) {
      int m = lst_s[i];
      Ks[i][tid] = K[((size_t)b * MM + m) * DD + tid];
      Vs[i][tid] = V[((size_t)b * MM + m) * DD + tid];
    }
  }
  __syncthreads();

  float bv = b3[tid];
  int hq = tid >> 5;

  for (int ch = 0; ch < EE / QCH; ++ch) {
    int q0 = ch * QCH;
    if (small) {
      // softmax weights for QCH*HH = 128 (q,h) pairs
      if (tid < QCH * HH) {
        int ql = tid >> 3, h = tid & 7;
        const float* qp = Q + ((size_t)b * EE + q0 + ql) * DD + h * DKK;
        float s[WMAX];
        float mx = -1e30f;
        for (int i = 0; i < cn; ++i) {
          float acc = 0.f;
          const float* kp = &Ks[i][h * DKK];
          for (int k = 0; k < DKK; ++k) acc = fmaf(qp[k], kp[k], acc);
          s[i] = acc * scale;
          mx = fmaxf(mx, s[i]);
        }
        float sum = 0.f;
        for (int i = 0; i < cn; ++i) { s[i] = __expf(s[i] - mx); sum += s[i]; }
        float inv = 1.0f / sum;
        for (int i = 0; i < cn; ++i) wl[ql][h][i] = s[i] * inv;
      }
      __syncthreads();
      for (int ql = 0; ql < QCH; ++ql) {
        float a = 0.f;
        for (int i = 0; i < cn; ++i) a = fmaf(wl[ql][hq][i], Vs[i][tid], a);
        av[ql][tid] = a;
      }
      __syncthreads();
    } else {
      // cn > 16: statistically ~never; redundant per-thread recompute, correct.
      for (int ql = 0; ql < QCH; ++ql) {
        const float* qp = Q + ((size_t)b * EE + q0 + ql) * DD + hq * DKK;
        float mx = -1e30f;
        for (int i = 0; i < cn; ++i) {
          int m = lst_s[i];
          const float* kp = K + ((size_t)b * MM + m) * DD + hq * DKK;
          float acc = 0.f;
          for (int k = 0; k < DKK; ++k) acc = fmaf(qp[k], kp[k], acc);
          mx = fmaxf(mx, acc * scale);
        }
        float sum = 0.f, a = 0.f;
        for (int i = 0; i < cn; ++i) {
          int m = lst_s[i];
          const float* kp = K + ((size_t)b * MM + m) * DD + hq * DKK;
          float acc = 0.f;
          for (int k = 0; k < DKK; ++k) acc = fmaf(qp[k], kp[k], acc);
          float w = __expf(acc * scale - mx);
          sum += w;
          a = fmaf(w, V[((size_t)b * MM + m) * DD + tid], a);
        }
        av[ql][tid] = a / sum;
      }
      __syncthreads();
    }
    // out[q0+ql][c] = av[ql][:] @ W3[:,c] + b3[c]
    for (int ql = 0; ql < QCH; ++ql) {
      float acc = bv;
#pragma unroll 4
      for (int d = 0; d < DD; ++d) acc = fmaf(av[ql][d], W3[(size_t)d * DD + tid], acc);
      int q = q0 + ql;
      int p = sideT ? (q * EE + em) : (em * EE + q);
      outp[((size_t)b * 4096 + p) * DD + tid] = acc;
    }
    __syncthreads();
  }
}

extern "C" void kernel_launch(void* const* d_in, const int* in_sizes, int n_in,
                              void* d_out, int out_size, void* d_ws, size_t ws_size,
                              hipStream_t stream) {
  const float* entities  = (const float*)d_in[0];
  const float* mentions  = (const float*)d_in[1];
  const float* sentences = (const float*)d_in[2];
  const int* sent_ids    = (const int*)d_in[3];
  const int* mention_eid = (const int*)d_in[4];
  const float* W_h = (const float*)d_in[5];
  const float* b_h = (const float*)d_in[6];
  const float* W_t = (const float*)d_in[7];
  const float* b_t = (const float*)d_in[8];
  float* outp = (float*)d_out;  // reference output dtype is float32

  // workspace ~5.3 MB
  float* f = (float*)d_ws;
  float* Qh = f;  f += BB * EE * DD;
  float* Qt = f;  f += BB * EE * DD;
  float* Kh = f;  f += BB * MM * DD;
  float* Kt = f;  f += BB * MM * DD;
  float* Vh = f;  f += BB * MM * DD;
  float* Vt = f;  f += BB * MM * DD;
  float* Vsh = f; f += BB * DD;
  float* Vst = f; f += BB * DD;
  int* cnt = (int*)f;
  int* lst = cnt + BB * EE;

  k_lists<<<BB, 64, 0, stream>>>(mention_eid, cnt, lst);

  k_proj<<<BB * EE / 4, DD, 0, stream>>>(entities, nullptr, EE, EE, W_h, b_h, Qh);
  k_proj<<<BB * EE / 4, DD, 0, stream>>>(entities, nullptr, EE, EE, W_t, b_t, Qt);
  k_proj<<<BB * MM / 4, DD, 0, stream>>>(sentences, sent_ids, MM, SSN, W_h + DD * DD, b_h + DD, Kh);
  k_proj<<<BB * MM / 4, DD, 0, stream>>>(sentences, sent_ids, MM, SSN, W_t + DD * DD, b_t + DD, Kt);
  k_proj<<<BB * MM / 4, DD, 0, stream>>>(mentions, nullptr, MM, MM, W_h + 2 * DD * DD, b_h + 2 * DD, Vh);
  k_proj<<<BB * MM / 4, DD, 0, stream>>>(mentions, nullptr, MM, MM, W_t + 2 * DD * DD, b_t + 2 * DD, Vt);

  k_vsum<<<BB, DD, 0, stream>>>(Vh, Vsh);
  k_vsum<<<BB, DD, 0, stream>>>(Vt, Vst);

  k_main2<<<BB * EE, DD, 0, stream>>>(Qh, Kh, Vh, Vsh, W_h + 3 * DD * DD, b_h + 3 * DD,
                                      cnt, lst, outp, 0);
  k_main2<<<BB * EE, DD, 0, stream>>>(Qt, Kt, Vt, Vst, W_t + 3 * DD * DD, b_t + 3 * DD,
                                      cnt, lst, outp + (size_t)BB * 4096 * DD, 1);
}

// Round 10
// 424.783 us; speedup vs baseline: 2.7174x; 2.7174x over previous
//
#include <hip/hip_runtime.h>
#include <hip/hip_bf16.h>

#define BB 8
#define EE 64
#define MM 128
#define SSN 32
#define DD 256
#define HH 8
#define DKK 32
#define WMAX 16
#define QCH 16   // queries per chunk in k_main3

// Build per-(b,e) mention lists: lst[(b*EE+e)*MM + k] = m-th mention with eid==e
__global__ void k_lists(const int* __restrict__ eid, int* __restrict__ cnt, int* __restrict__ lst) {
  int b = blockIdx.x;
  __shared__ int eid_s[MM];
  for (int m = threadIdx.x; m < MM; m += blockDim.x) eid_s[m] = eid[b * MM + m];
  __syncthreads();
  int e = threadIdx.x;  // blockDim = 64
  int c = 0;
  int* lp = lst + (b * EE + e) * MM;
  for (int m = 0; m < MM; ++m)
    if (eid_s[m] == e) lp[c++] = m;
  cnt[b * EE + e] = c;
}

// out[r, c] = sum_k A[src(r), k] * W[k, c] + bias[c], 8 rows/block, register-tiled
__global__ __launch_bounds__(256) void k_proj8(
    const float* __restrict__ A, const int* __restrict__ gather,
    int rowsPerB, int srcRowsPerB,
    const float* __restrict__ W, const float* __restrict__ bias,
    float* __restrict__ out) {
  int r0 = blockIdx.x * 8;
  int c = threadIdx.x;  // 256 threads
  __shared__ float a_s[8][DD];
#pragma unroll
  for (int i = 0; i < 8; ++i) {
    int r = r0 + i;
    int b = r / rowsPerB, rr = r - b * rowsPerB;
    int sr = gather ? gather[b * rowsPerB + rr] : rr;
    if (sr < 0) sr = 0;
    if (sr >= srcRowsPerB) sr = srcRowsPerB - 1;
    a_s[i][c] = A[((size_t)b * srcRowsPerB + sr) * DD + c];
  }
  __syncthreads();
  float acc[8];
#pragma unroll
  for (int i = 0; i < 8; ++i) acc[i] = 0.f;
  for (int k = 0; k < DD; k += 4) {
    float w0 = W[(size_t)(k + 0) * DD + c];
    float w1 = W[(size_t)(k + 1) * DD + c];
    float w2 = W[(size_t)(k + 2) * DD + c];
    float w3 = W[(size_t)(k + 3) * DD + c];
#pragma unroll
    for (int i = 0; i < 8; ++i) {
      float4 a = *(const float4*)&a_s[i][k];
      acc[i] = fmaf(a.x, w0, fmaf(a.y, w1, fmaf(a.z, w2, fmaf(a.w, w3, acc[i]))));
    }
  }
  float bv = bias[c];
#pragma unroll
  for (int i = 0; i < 8; ++i)
    out[((size_t)r0 + i) * DD + c] = acc[i] + bv;
}

// Vsum[b, d] = sum_m V[b, m, d]
__global__ void k_vsum(const float* __restrict__ V, float* __restrict__ Vsum) {
  int b = blockIdx.x;
  int d = threadIdx.x;
  float s = 0.f;
  for (int m = 0; m < MM; ++m) s += V[((size_t)b * MM + m) * DD + d];
  Vsum[b * DD + d] = s;
}

// One block per (b, mask-entity em). 64 output rows; register-tiled W3 apply.
// side h (sideT=0): p = em*64 + q ; side t (sideT=1): p = q*64 + em
__global__ __launch_bounds__(256) void k_main3(
    const float* __restrict__ Q, const float* __restrict__ K,
    const float* __restrict__ V, const float* __restrict__ Vsum,
    const float* __restrict__ W3, const float* __restrict__ b3,
    const int* __restrict__ cnt, const int* __restrict__ lst,
    float* __restrict__ outp, int sideT) {
  int blk = blockIdx.x;  // b*EE + em
  int b = blk >> 6, em = blk & 63;
  int tid = threadIdx.x;
  __shared__ float wl[QCH][HH][WMAX];  // 8 KB
  __shared__ float av[QCH][DD];        // 16 KB
  __shared__ int lst_s[MM];
  __shared__ int cn_s;
  if (tid == 0) cn_s = cnt[blk];
  for (int m = tid; m < MM; m += 256) lst_s[m] = lst[blk * MM + m];
  __syncthreads();
  int cn = cn_s;
  const float scale = 0.17677669529663687f;  // 1/sqrt(32)
  float bv = b3[tid];

  if (cn == 0) {
    // all masked -> uniform softmax over all 128 mentions; same row for every q
    float acc = bv;
    for (int d = 0; d < DD; d += 4) {
      float w0 = W3[(size_t)(d + 0) * DD + tid];
      float w1 = W3[(size_t)(d + 1) * DD + tid];
      float w2 = W3[(size_t)(d + 2) * DD + tid];
      float w3 = W3[(size_t)(d + 3) * DD + tid];
      const float4 vs = *(const float4*)&Vsum[b * DD + d];
      acc = fmaf(vs.x * (1.0f / 128.0f), w0, acc);
      acc = fmaf(vs.y * (1.0f / 128.0f), w1, acc);
      acc = fmaf(vs.z * (1.0f / 128.0f), w2, acc);
      acc = fmaf(vs.w * (1.0f / 128.0f), w3, acc);
    }
    for (int q = 0; q < EE; ++q) {
      int p = sideT ? (q * EE + em) : (em * EE + q);
      outp[((size_t)b * 4096 + p) * DD + tid] = acc;
    }
    return;
  }

  bool small = (cn <= WMAX);
  int hq = tid >> 5;

  for (int ch = 0; ch < EE / QCH; ++ch) {
    int q0 = ch * QCH;
    if (small) {
      // phase B: softmax weights for QCH*HH = 128 (q,h) pairs (K rows from L2)
      if (tid < QCH * HH) {
        int ql = tid >> 3, h = tid & 7;
        const float* qp = Q + ((size_t)b * EE + q0 + ql) * DD + h * DKK;
        float s[WMAX];
        float mx = -1e30f;
        for (int i = 0; i < cn; ++i) {
          const float* kp = K + ((size_t)b * MM + lst_s[i]) * DD + h * DKK;
          float acc = 0.f;
#pragma unroll
          for (int k = 0; k < DKK; ++k) acc = fmaf(qp[k], kp[k], acc);
          s[i] = acc * scale;
          mx = fmaxf(mx, s[i]);
        }
        float sum = 0.f;
        for (int i = 0; i < cn; ++i) { s[i] = __expf(s[i] - mx); sum += s[i]; }
        float inv = 1.0f / sum;
        for (int i = 0; i < cn; ++i) wl[ql][h][i] = s[i] * inv;
      }
      __syncthreads();
      // phase C: av[ql][tid] = sum_i wl[ql][hq][i] * V[m_i][tid] (V-row reuse across ql)
      {
        float avr[QCH];
#pragma unroll
        for (int ql = 0; ql < QCH; ++ql) avr[ql] = 0.f;
        for (int i = 0; i < cn; ++i) {
          float v = V[((size_t)b * MM + lst_s[i]) * DD + tid];
#pragma unroll
          for (int ql = 0; ql < QCH; ++ql)
            avr[ql] = fmaf(wl[ql][hq][i], v, avr[ql]);
        }
#pragma unroll
        for (int ql = 0; ql < QCH; ++ql) av[ql][tid] = avr[ql];
      }
      __syncthreads();
    } else {
      // cn > 16: statistically ~never; redundant per-thread recompute, correct.
      for (int ql = 0; ql < QCH; ++ql) {
        const float* qp = Q + ((size_t)b * EE + q0 + ql) * DD + hq * DKK;
        float mx = -1e30f;
        for (int i = 0; i < cn; ++i) {
          const float* kp = K + ((size_t)b * MM + lst_s[i]) * DD + hq * DKK;
          float acc = 0.f;
          for (int k = 0; k < DKK; ++k) acc = fmaf(qp[k], kp[k], acc);
          mx = fmaxf(mx, acc * scale);
        }
        float sum = 0.f, a = 0.f;
        for (int i = 0; i < cn; ++i) {
          int m = lst_s[i];
          const float* kp = K + ((size_t)b * MM + m) * DD + hq * DKK;
          float acc = 0.f;
          for (int k = 0; k < DKK; ++k) acc = fmaf(qp[k], kp[k], acc);
          float w = __expf(acc * scale - mx);
          sum += w;
          a = fmaf(w, V[((size_t)b * MM + m) * DD + tid], a);
        }
        av[ql][tid] = a / sum;
      }
      __syncthreads();
    }
    // phase D: register-tiled out[q0+ql][c] = av[ql][:] @ W3[:,c] + b3[c]
    {
      float acc[QCH];
#pragma unroll
      for (int ql = 0; ql < QCH; ++ql) acc[ql] = bv;
      for (int d = 0; d < DD; d += 4) {
        float w0 = W3[(size_t)(d + 0) * DD + tid];
        float w1 = W3[(size_t)(d + 1) * DD + tid];
        float w2 = W3[(size_t)(d + 2) * DD + tid];
        float w3 = W3[(size_t)(d + 3) * DD + tid];
#pragma unroll
        for (int ql = 0; ql < QCH; ++ql) {
          float4 a = *(const float4*)&av[ql][d];
          acc[ql] = fmaf(a.x, w0, fmaf(a.y, w1, fmaf(a.z, w2, fmaf(a.w, w3, acc[ql]))));
        }
      }
#pragma unroll
      for (int ql = 0; ql < QCH; ++ql) {
        int q = q0 + ql;
        int p = sideT ? (q * EE + em) : (em * EE + q);
        outp[((size_t)b * 4096 + p) * DD + tid] = acc[ql];
      }
    }
    __syncthreads();  // av/wl reuse in next chunk
  }
}

extern "C" void kernel_launch(void* const* d_in, const int* in_sizes, int n_in,
                              void* d_out, int out_size, void* d_ws, size_t ws_size,
                              hipStream_t stream) {
  const float* entities  = (const float*)d_in[0];
  const float* mentions  = (const float*)d_in[1];
  const float* sentences = (const float*)d_in[2];
  const int* sent_ids    = (const int*)d_in[3];
  const int* mention_eid = (const int*)d_in[4];
  const float* W_h = (const float*)d_in[5];
  const float* b_h = (const float*)d_in[6];
  const float* W_t = (const float*)d_in[7];
  const float* b_t = (const float*)d_in[8];
  float* outp = (float*)d_out;  // output dtype: float32

  // workspace ~5.3 MB
  float* f = (float*)d_ws;
  float* Qh = f;  f += BB * EE * DD;
  float* Qt = f;  f += BB * EE * DD;
  float* Kh = f;  f += BB * MM * DD;
  float* Kt = f;  f += BB * MM * DD;
  float* Vh = f;  f += BB * MM * DD;
  float* Vt = f;  f += BB * MM * DD;
  float* Vsh = f; f += BB * DD;
  float* Vst = f; f += BB * DD;
  int* cnt = (int*)f;
  int* lst = cnt + BB * EE;

  k_lists<<<BB, 64, 0, stream>>>(mention_eid, cnt, lst);

  k_proj8<<<BB * EE / 8, DD, 0, stream>>>(entities, nullptr, EE, EE, W_h, b_h, Qh);
  k_proj8<<<BB * EE / 8, DD, 0, stream>>>(entities, nullptr, EE, EE, W_t, b_t, Qt);
  k_proj8<<<BB * MM / 8, DD, 0, stream>>>(sentences, sent_ids, MM, SSN, W_h + DD * DD, b_h + DD, Kh);
  k_proj8<<<BB * MM / 8, DD, 0, stream>>>(sentences, sent_ids, MM, SSN, W_t + DD * DD, b_t + DD, Kt);
  k_proj8<<<BB * MM / 8, DD, 0, stream>>>(mentions, nullptr, MM, MM, W_h + 2 * DD * DD, b_h + 2 * DD, Vh);
  k_proj8<<<BB * MM / 8, DD, 0, stream>>>(mentions, nullptr, MM, MM, W_t + 2 * DD * DD, b_t + 2 * DD, Vt);

  k_vsum<<<BB, DD, 0, stream>>>(Vh, Vsh);
  k_vsum<<<BB, DD, 0, stream>>>(Vt, Vst);

  k_main3<<<BB * EE, DD, 0, stream>>>(Qh, Kh, Vh, Vsh, W_h + 3 * DD * DD, b_h + 3 * DD,
                                      cnt, lst, outp, 0);
  k_main3<<<BB * EE, DD, 0, stream>>>(Qt, Kt, Vt, Vst, W_t + 3 * DD * DD, b_t + 3 * DD,
                                      cnt, lst, outp + (size_t)BB * 4096 * DD, 1);
}

// Round 14
// 283.932 us; speedup vs baseline: 4.0655x; 1.4961x over previous
//
#include <hip/hip_runtime.h>
#include <hip/hip_bf16.h>

#define BB 8
#define EE 64
#define MM 128
#define SSN 32
#define DD 256
#define HH 8
#define DKK 32
#define WMAX 16
#define QCH 16   // queries per chunk-block in k_main4

// Build per-(b,e) mention lists: lst[(b*EE+e)*MM + k] = m-th mention with eid==e
__global__ void k_lists(const int* __restrict__ eid, int* __restrict__ cnt, int* __restrict__ lst) {
  int b = blockIdx.x;
  __shared__ int eid_s[MM];
  for (int m = threadIdx.x; m < MM; m += blockDim.x) eid_s[m] = eid[b * MM + m];
  __syncthreads();
  int e = threadIdx.x;  // blockDim = 64
  int c = 0;
  int* lp = lst + (b * EE + e) * MM;
  for (int m = 0; m < MM; ++m)
    if (eid_s[m] == e) lp[c++] = m;
  cnt[b * EE + e] = c;
}

// All 6 projections in one launch. 8 rows/block, register-tiled.
// id 0: Qh(entities,Wh0)  1: Qt  2: Kh(sentences gather,Wh1)  3: Kt  4: Vh(mentions,Wh2)  5: Vt
__global__ __launch_bounds__(256) void k_proj_all(
    const float* __restrict__ entities, const float* __restrict__ mentions,
    const float* __restrict__ sentences, const int* __restrict__ sent_ids,
    const float* __restrict__ W_h, const float* __restrict__ b_h,
    const float* __restrict__ W_t, const float* __restrict__ b_t,
    float* __restrict__ Qh, float* __restrict__ Qt,
    float* __restrict__ Kh, float* __restrict__ Kt,
    float* __restrict__ Vh, float* __restrict__ Vt) {
  int bid = blockIdx.x;
  const float *A, *W, *bias;
  const int* gather = nullptr;
  float* out;
  int rowsPerB, srcRowsPerB, r0;
  if (bid < 128) {  // Q: 64 blocks each side
    int side = bid >> 6;
    r0 = (bid & 63) * 8;
    A = entities; rowsPerB = EE; srcRowsPerB = EE;
    W = side ? W_t : W_h; bias = side ? b_t : b_h; out = side ? Qt : Qh;
  } else if (bid < 384) {  // K: 128 blocks each side
    int side = (bid - 128) >> 7;
    r0 = ((bid - 128) & 127) * 8;
    A = sentences; gather = sent_ids; rowsPerB = MM; srcRowsPerB = SSN;
    W = (side ? W_t : W_h) + DD * DD; bias = (side ? b_t : b_h) + DD;
    out = side ? Kt : Kh;
  } else {  // V: 128 blocks each side
    int side = (bid - 384) >> 7;
    r0 = ((bid - 384) & 127) * 8;
    A = mentions; rowsPerB = MM; srcRowsPerB = MM;
    W = (side ? W_t : W_h) + 2 * DD * DD; bias = (side ? b_t : b_h) + 2 * DD;
    out = side ? Vt : Vh;
  }
  int c = threadIdx.x;
  __shared__ float a_s[8][DD];
#pragma unroll
  for (int i = 0; i < 8; ++i) {
    int r = r0 + i;
    int b = r / rowsPerB, rr = r - b * rowsPerB;
    int sr = gather ? gather[b * rowsPerB + rr] : rr;
    if (sr < 0) sr = 0;
    if (sr >= srcRowsPerB) sr = srcRowsPerB - 1;
    a_s[i][c] = A[((size_t)b * srcRowsPerB + sr) * DD + c];
  }
  __syncthreads();
  float acc[8];
#pragma unroll
  for (int i = 0; i < 8; ++i) acc[i] = 0.f;
  for (int k = 0; k < DD; k += 4) {
    float w0 = W[(size_t)(k + 0) * DD + c];
    float w1 = W[(size_t)(k + 1) * DD + c];
    float w2 = W[(size_t)(k + 2) * DD + c];
    float w3 = W[(size_t)(k + 3) * DD + c];
#pragma unroll
    for (int i = 0; i < 8; ++i) {
      float4 a = *(const float4*)&a_s[i][k];
      acc[i] = fmaf(a.x, w0, fmaf(a.y, w1, fmaf(a.z, w2, fmaf(a.w, w3, acc[i]))));
    }
  }
  float bv = bias[c];
#pragma unroll
  for (int i = 0; i < 8; ++i)
    out[((size_t)r0 + i) * DD + c] = acc[i] + bv;
}

// Vsum for both sides in one launch: blocks 0..7 -> Vh, 8..15 -> Vt
__global__ void k_vsum2(const float* __restrict__ Vh, const float* __restrict__ Vt,
                        float* __restrict__ Vsh, float* __restrict__ Vst) {
  int g = blockIdx.x;
  const float* V = (g < BB) ? Vh : Vt;
  float* Vs = (g < BB) ? Vsh : Vst;
  int b = g & 7;
  int d = threadIdx.x;
  float s = 0.f;
  for (int m = 0; m < MM; ++m) s += V[((size_t)b * MM + m) * DD + d];
  Vs[b * DD + d] = s;
}

// One block per (side, b, em, chunk). 16 output rows each.
// side h: p = em*64 + q ; side t: p = q*64 + em
__global__ __launch_bounds__(256) void k_main4(
    const float* __restrict__ Qh, const float* __restrict__ Qt,
    const float* __restrict__ Kh, const float* __restrict__ Kt,
    const float* __restrict__ Vh, const float* __restrict__ Vt,
    const float* __restrict__ Vsh, const float* __restrict__ Vst,
    const float* __restrict__ W_h, const float* __restrict__ b_h,
    const float* __restrict__ W_t, const float* __restrict__ b_t,
    const int* __restrict__ cnt, const int* __restrict__ lst,
    float* __restrict__ outp) {
  int blk = blockIdx.x;            // [0, 2*BB*EE*4)
  int side = blk >> 11;
  int rem = blk & 2047;
  int bem = rem >> 2, ch = rem & 3;
  int b = bem >> 6, em = bem & 63;
  int q0 = ch * QCH;
  const float* Q = side ? Qt : Qh;
  const float* K = side ? Kt : Kh;
  const float* V = side ? Vt : Vh;
  const float* Vsum = side ? Vst : Vsh;
  const float* W3 = (side ? W_t : W_h) + 3 * DD * DD;
  const float* b3 = (side ? b_t : b_h) + 3 * DD;
  float* out = outp + (size_t)side * BB * 4096 * DD;

  int tid = threadIdx.x;
  __shared__ float wl[QCH][HH][WMAX];  // 8 KB
  __shared__ float av[QCH][DD];        // 16 KB
  __shared__ int lst_s[MM];
  __shared__ int cn_s;
  if (tid == 0) cn_s = cnt[bem];
  for (int m = tid; m < MM; m += 256) lst_s[m] = lst[bem * MM + m];
  __syncthreads();
  int cn = cn_s;
  const float scale = 0.17677669529663687f;  // 1/sqrt(32)
  float bv = b3[tid];

  if (cn == 0) {
    // all masked -> uniform softmax over all 128 mentions; same row for all q
    float acc = bv;
    for (int d = 0; d < DD; d += 4) {
      float w0 = W3[(size_t)(d + 0) * DD + tid];
      float w1 = W3[(size_t)(d + 1) * DD + tid];
      float w2 = W3[(size_t)(d + 2) * DD + tid];
      float w3 = W3[(size_t)(d + 3) * DD + tid];
      const float4 vs = *(const float4*)&Vsum[b * DD + d];
      acc = fmaf(vs.x * (1.0f / 128.0f), w0, acc);
      acc = fmaf(vs.y * (1.0f / 128.0f), w1, acc);
      acc = fmaf(vs.z * (1.0f / 128.0f), w2, acc);
      acc = fmaf(vs.w * (1.0f / 128.0f), w3, acc);
    }
    for (int ql = 0; ql < QCH; ++ql) {
      int q = q0 + ql;
      int p = side ? (q * EE + em) : (em * EE + q);
      out[((size_t)b * 4096 + p) * DD + tid] = acc;
    }
    return;
  }

  bool small = (cn <= WMAX);
  int hq = tid >> 5;

  if (small) {
    // phase B: softmax weights for QCH*HH = 128 (q,h) pairs
    if (tid < QCH * HH) {
      int ql = tid >> 3, h = tid & 7;
      const float* qp = Q + ((size_t)b * EE + q0 + ql) * DD + h * DKK;
      float s[WMAX];
      float mx = -1e30f;
      for (int i = 0; i < cn; ++i) {
        const float* kp = K + ((size_t)b * MM + lst_s[i]) * DD + h * DKK;
        float acc = 0.f;
#pragma unroll
        for (int k = 0; k < DKK; ++k) acc = fmaf(qp[k], kp[k], acc);
        s[i] = acc * scale;
        mx = fmaxf(mx, s[i]);
      }
      float sum = 0.f;
      for (int i = 0; i < cn; ++i) { s[i] = __expf(s[i] - mx); sum += s[i]; }
      float inv = 1.0f / sum;
      for (int i = 0; i < cn; ++i) wl[ql][h][i] = s[i] * inv;
    }
    __syncthreads();
    // phase C: av[ql][tid] = sum_i wl[ql][hq][i] * V[m_i][tid]
    {
      float avr[QCH];
#pragma unroll
      for (int ql = 0; ql < QCH; ++ql) avr[ql] = 0.f;
      for (int i = 0; i < cn; ++i) {
        float v = V[((size_t)b * MM + lst_s[i]) * DD + tid];
#pragma unroll
        for (int ql = 0; ql < QCH; ++ql)
          avr[ql] = fmaf(wl[ql][hq][i], v, avr[ql]);
      }
#pragma unroll
      for (int ql = 0; ql < QCH; ++ql) av[ql][tid] = avr[ql];
    }
    __syncthreads();
  } else {
    // cn > 16: statistically ~never; redundant per-thread recompute, correct.
    for (int ql = 0; ql < QCH; ++ql) {
      const float* qp = Q + ((size_t)b * EE + q0 + ql) * DD + hq * DKK;
      float mx = -1e30f;
      for (int i = 0; i < cn; ++i) {
        const float* kp = K + ((size_t)b * MM + lst_s[i]) * DD + hq * DKK;
        float acc = 0.f;
        for (int k = 0; k < DKK; ++k) acc = fmaf(qp[k], kp[k], acc);
        mx = fmaxf(mx, acc * scale);
      }
      float sum = 0.f, a = 0.f;
      for (int i = 0; i < cn; ++i) {
        int m = lst_s[i];
        const float* kp = K + ((size_t)b * MM + m) * DD + hq * DKK;
        float acc = 0.f;
        for (int k = 0; k < DKK; ++k) acc = fmaf(qp[k], kp[k], acc);
        float w = __expf(acc * scale - mx);
        sum += w;
        a = fmaf(w, V[((size_t)b * MM + m) * DD + tid], a);
      }
      av[ql][tid] = a / sum;
    }
    __syncthreads();
  }

  // phase D: register-tiled out[q0+ql][c] = av[ql][:] @ W3[:,c] + b3[c]
  {
    float acc[QCH];
#pragma unroll
    for (int ql = 0; ql < QCH; ++ql) acc[ql] = bv;
    for (int d = 0; d < DD; d += 4) {
      float w0 = W3[(size_t)(d + 0) * DD + tid];
      float w1 = W3[(size_t)(d + 1) * DD + tid];
      float w2 = W3[(size_t)(d + 2) * DD + tid];
      float w3 = W3[(size_t)(d + 3) * DD + tid];
#pragma unroll
      for (int ql = 0; ql < QCH; ++ql) {
        float4 a = *(const float4*)&av[ql][d];
        acc[ql] = fmaf(a.x, w0, fmaf(a.y, w1, fmaf(a.z, w2, fmaf(a.w, w3, acc[ql]))));
      }
    }
#pragma unroll
    for (int ql = 0; ql < QCH; ++ql) {
      int q = q0 + ql;
      int p = side ? (q * EE + em) : (em * EE + q);
      out[((size_t)b * 4096 + p) * DD + tid] = acc[ql];
    }
  }
}

extern "C" void kernel_launch(void* const* d_in, const int* in_sizes, int n_in,
                              void* d_out, int out_size, void* d_ws, size_t ws_size,
                              hipStream_t stream) {
  const float* entities  = (const float*)d_in[0];
  const float* mentions  = (const float*)d_in[1];
  const float* sentences = (const float*)d_in[2];
  const int* sent_ids    = (const int*)d_in[3];
  const int* mention_eid = (const int*)d_in[4];
  const float* W_h = (const float*)d_in[5];
  const float* b_h = (const float*)d_in[6];
  const float* W_t = (const float*)d_in[7];
  const float* b_t = (const float*)d_in[8];
  float* outp = (float*)d_out;  // output dtype: float32

  // workspace ~5.3 MB
  float* f = (float*)d_ws;
  float* Qh = f;  f += BB * EE * DD;
  float* Qt = f;  f += BB * EE * DD;
  float* Kh = f;  f += BB * MM * DD;
  float* Kt = f;  f += BB * MM * DD;
  float* Vh = f;  f += BB * MM * DD;
  float* Vt = f;  f += BB * MM * DD;
  float* Vsh = f; f += BB * DD;
  float* Vst = f; f += BB * DD;
  int* cnt = (int*)f;
  int* lst = cnt + BB * EE;

  k_lists<<<BB, 64, 0, stream>>>(mention_eid, cnt, lst);

  k_proj_all<<<640, DD, 0, stream>>>(entities, mentions, sentences, sent_ids,
                                     W_h, b_h, W_t, b_t, Qh, Qt, Kh, Kt, Vh, Vt);

  k_vsum2<<<2 * BB, DD, 0, stream>>>(Vh, Vt, Vsh, Vst);

  k_main4<<<2 * BB * EE * 4, DD, 0, stream>>>(Qh, Qt, Kh, Kt, Vh, Vt, Vsh, Vst,
                                              W_h, b_h, W_t, b_t, cnt, lst, outp);
}